// Round 3
// baseline (71.101 us; speedup 1.0000x reference)
//
#include <hip/hip_runtime.h>
#include <math.h>

// Problem constants (match reference)
#define Bq 4
#define Nq 80
#define Mq 16
#define CHq 64
#define GAMMAq 4.0f
#define EPSq 1e-6f
#define NCA 46      // pcA comps: A00 0-2, A10 3-5, C01 6-14, P0 15-23, P1 24-32, P2 33-41, r1 42-45
#define NCB 42      // pcB comps: wr2-mixed versions of comps 0..41
#define NBLK (Bq * Nq)   // 320 blocks

// ---------------------------------------------------------------------------
// Device-wide barrier: 8 sub-counters (128B apart) + 1 root. Counters are
// zeroed by hipMemsetAsync before each launch (poison-safe). Blocks are
// guaranteed co-resident: 320 blocks x 256 thr, ~17KB LDS -> >=4 blocks/CU.
// ---------------------------------------------------------------------------
__device__ __forceinline__ void gridBarrier(unsigned* bar) {
    __syncthreads();                       // drains vmcnt: all our global writes done
    if (threadIdx.x == 0) {
        __threadfence();                   // agent-scope release of pcA/pcB stores
        const unsigned sub = blockIdx.x & 7;
        const unsigned prev = __hip_atomic_fetch_add(&bar[sub * 32], 1u,
                                  __ATOMIC_ACQ_REL, __HIP_MEMORY_SCOPE_AGENT);
        if (prev + 1 == (NBLK / 8)) {
            __hip_atomic_fetch_add(&bar[512], 1u,
                                  __ATOMIC_ACQ_REL, __HIP_MEMORY_SCOPE_AGENT);
        }
        int spins = 0;
        while (__hip_atomic_load(&bar[512], __ATOMIC_ACQUIRE,
                                 __HIP_MEMORY_SCOPE_AGENT) < 8u) {
            __builtin_amdgcn_s_sleep(2);
            if (++spins > 20000000) break; // bail-out: fail fast, never hang 600s
        }
        __threadfence();                   // acquire: invalidate stale cache lines
    }
    __syncthreads();
}

// ---------------------------------------------------------------------------
// One fused kernel. Block nb owns (n = nb/80, b = nb%80) for phase B and
// owns na = nb for phase A (each (n,a) precomputed exactly once).
//
// Phase A (96 active threads = 16u x 3k x 2 v-halves):
//   pcA[na][c][u] : weight (x) h_nei contractions + r1 = SI(x)
//   pcB[na][c][u] : wr2-mixed copies (r2 = SI(h_conv) folded into the pair
//                   contraction via linearity) -> phase B needs NO cross-
//                   thread communication and NO barriers in its a-loop.
// Grid barrier.
// Phase B (256 threads = 16 a-groups x 16 u): 5 barrier-free a-iterations,
//   per-pair h_conv + r2 + gate, accumulate, shuffle-reduce, epilogue.
// ---------------------------------------------------------------------------
__global__ __launch_bounds__(256) void se3_fused(
    const float* __restrict__ x,       // [B][CH][N]
    const float* __restrict__ h_nei,   // [B][CH][N]
    const float* __restrict__ hdiff,   // [B][N][N][3]
    const float* __restrict__ mask,    // [B][N][N]
    const float* __restrict__ w00,     // [M][M][3]
    const float* __restrict__ w10,
    const float* __restrict__ w01,
    const float* __restrict__ w11,     // [3][M][M][3]
    const float* __restrict__ wr10,    // [M][M]
    const float* __restrict__ wr11,
    const float* __restrict__ wr20,    // [M][M]
    const float* __restrict__ wr21,
    const float* __restrict__ wz0,     // [M][2M]
    const float* __restrict__ wz1,
    const float* __restrict__ wp0,
    const float* __restrict__ wp1,
    float* __restrict__ pcA,
    float* __restrict__ pcB,
    unsigned* __restrict__ bar,
    float* __restrict__ out)           // [B][CH][N]
{
    const int nb  = blockIdx.x;        // 0..319
    const int tid = threadIdx.x;

    __shared__ float psh[2][42][16];
    __shared__ float r1sh[2][4][16];
    __shared__ float wsh[4][512];      // wz0, wz1, wp0, wp1
    __shared__ float redW[4][8][16];
    __shared__ float sumHs[64], sumGs[64];

    // ---------------- Phase A: na = nb ----------------
    {
        const int na = nb;
        const int n  = na / Nq, a = na - (na / Nq) * Nq;

        if (tid < 96) {
            const int u    = tid & 15;
            const int kk   = tid >> 4;        // 0..5
            const int k    = kk % 3;
            const int half = kk / 3;
            const int v0   = half * 8;

            const float* hb = h_nei + (size_t)n * CHq * Nq + a;
            float s[8], V[8][3];
#pragma unroll
            for (int i = 0; i < 8; ++i) s[i] = hb[(v0 + i) * Nq];
#pragma unroll
            for (int i = 0; i < 8; ++i)
#pragma unroll
                for (int j = 0; j < 3; ++j) V[i][j] = hb[(16 + (v0 + i) * 3 + j) * Nq];

            float a00 = 0.f, a10 = 0.f;
            float c[3] = {0.f,0.f,0.f}, p0[3] = {0.f,0.f,0.f};
            float p1[3] = {0.f,0.f,0.f}, p2[3] = {0.f,0.f,0.f};
#pragma unroll
            for (int i = 0; i < 8; ++i) {
                const int v = v0 + i;
                a00 += w00[(u * 16 + v) * 3 + k] * s[i];
                a10 += w10[(u * 16 + v) * 3 + k] * s[i];
                const float w01v = w01[(u * 16 + v) * 3 + k];
                const float w110 = w11[((0 * 16 + u) * 16 + v) * 3 + k];
                const float w111 = w11[((1 * 16 + u) * 16 + v) * 3 + k];
                const float w112 = w11[((2 * 16 + u) * 16 + v) * 3 + k];
#pragma unroll
                for (int j = 0; j < 3; ++j) {
                    c[j]  += w01v * V[i][j];
                    p0[j] += w110 * V[i][j];
                    p1[j] += w111 * V[i][j];
                    p2[j] += w112 * V[i][j];
                }
            }
            psh[half][0 + k][u] = a00;
            psh[half][3 + k][u] = a10;
#pragma unroll
            for (int j = 0; j < 3; ++j) {
                psh[half][6  + k * 3 + j][u] = c[j];
                psh[half][15 + k * 3 + j][u] = p0[j];
                psh[half][24 + k * 3 + j][u] = p1[j];
                psh[half][33 + k * 3 + j][u] = p2[j];
            }

            if (k == 0) {   // r1 partial for this v-half
                const float* xb = x + (size_t)n * CHq * Nq + a;
                float r1s = 0.f, r1v[3] = {0.f, 0.f, 0.f};
#pragma unroll
                for (int i = 0; i < 8; ++i) {
                    const int v = v0 + i;
                    r1s += wr10[u * 16 + v] * xb[v * Nq];
                    const float wv = wr11[u * 16 + v];
#pragma unroll
                    for (int j = 0; j < 3; ++j) r1v[j] += wv * xb[(16 + v * 3 + j) * Nq];
                }
                r1sh[half][0][u] = r1s;
#pragma unroll
                for (int j = 0; j < 3; ++j) r1sh[half][1 + j][u] = r1v[j];
            }
        }
        __syncthreads();

        // A1.5: sum v-halves, write pcA
        if (tid < 96) {
            const int u  = tid & 15;
            const int kk = tid >> 4;
            float* gA = pcA + (size_t)na * NCA * 16;
#pragma unroll
            for (int c = kk * 7; c < kk * 7 + 7; ++c) {
                const float vsum = psh[0][c][u] + psh[1][c][u];
                psh[0][c][u] = vsum;
                gA[c * 16 + u] = vsum;
            }
            if (kk == 0) {
#pragma unroll
                for (int j = 0; j < 4; ++j)
                    gA[(42 + j) * 16 + u] = r1sh[0][j][u] + r1sh[1][j][u];
            }
        }
        __syncthreads();

        // A2: wr2-mix (r2 folded into pair contraction), write pcB
        if (tid < 96) {
            const int u  = tid & 15;
            const int kk = tid >> 4;
            float* gB = pcB + (size_t)na * NCB * 16;
#pragma unroll
            for (int c = kk * 7; c < kk * 7 + 7; ++c) {
                const bool scalarType = (c < 3) || (c >= 6 && c < 15);
                const float* W = scalarType ? wr20 : wr21;
                float acc = 0.f;
#pragma unroll
                for (int v = 0; v < 16; ++v) acc += W[u * 16 + v] * psh[0][c][v];
                gB[c * 16 + u] = acc;
            }
        }

        // preload epilogue weights into LDS (completes before barrier exit)
#pragma unroll
        for (int i = 0; i < 2; ++i) {
            const int idx = tid + i * 256;
            wsh[0][idx] = wz0[idx];
            wsh[1][idx] = wz1[idx];
            wsh[2][idx] = wp0[idx];
            wsh[3][idx] = wp1[idx];
        }
    }

    // ---------------- grid barrier ----------------
    gridBarrier(bar);

    // ---------------- Phase B: (n, b) = (nb/80, nb%80) ----------------
    const int n     = nb / Nq;
    const int bnode = nb - n * Nq;
    const int g     = tid >> 4;        // a-group 0..15
    const int u     = tid & 15;        // channel 0..15

    float shs = 0.f, shv0 = 0.f, shv1 = 0.f, shv2 = 0.f;
    float sgs = 0.f, sgv0 = 0.f, sgv1 = 0.f, sgv2 = 0.f;

    const float* baseA = pcA + (size_t)(n * Nq) * NCA * 16 + u;
    const float* baseB = pcB + (size_t)(n * Nq) * NCB * 16 + u;
    const float* drow  = hdiff + (size_t)(n * Nq + bnode) * Nq * 3;
    const float* mrow  = mask  + (size_t)(n * Nq + bnode) * Nq;
    const float third  = 1.0f / 3.0f;

    for (int it = 0; it < 5; ++it) {
        const int a = it * 16 + g;

        const float d0 = drow[a * 3 + 0], d1 = drow[a * 3 + 1], d2 = drow[a * 3 + 2];
        const float m  = mrow[a];

        const float rad = sqrtf(d0 * d0 + d1 * d1 + d2 * d2 + EPSq);
        const float inv = 1.0f / rad;
        const float nh0 = d0 * inv, nh1 = d1 * inv, nh2 = d2 * inv;
        float rb[3];
        rb[0] = expf(-GAMMAq * rad * rad);
        { float t1 = rad - 0.5f; rb[1] = expf(-GAMMAq * t1 * t1); }
        { float t2 = rad - 1.0f; rb[2] = expf(-GAMMAq * t2 * t2); }

        const float* pA = baseA + (size_t)a * NCA * 16;
        const float* pB = baseB + (size_t)a * NCB * 16;

        // --- h_conv pair from pcA ---
        float as_ = 0.f, a10 = 0.f;
        float c01[3] = {0.f,0.f,0.f}, p0[3] = {0.f,0.f,0.f};
        float p1[3] = {0.f,0.f,0.f}, p2[3] = {0.f,0.f,0.f};
        // --- r2 pair from pcB ---
        float bs_ = 0.f, b10 = 0.f;
        float bc01[3] = {0.f,0.f,0.f}, bp0[3] = {0.f,0.f,0.f};
        float bp1[3] = {0.f,0.f,0.f}, bp2[3] = {0.f,0.f,0.f};
#pragma unroll
        for (int k = 0; k < 3; ++k) {
            const float r = rb[k];
            as_ += r * pA[(0 + k) * 16];
            a10 += r * pA[(3 + k) * 16];
            bs_ += r * pB[(0 + k) * 16];
            b10 += r * pB[(3 + k) * 16];
#pragma unroll
            for (int j = 0; j < 3; ++j) {
                c01[j]  += r * pA[(6  + k * 3 + j) * 16];
                p0[j]   += r * pA[(15 + k * 3 + j) * 16];
                p1[j]   += r * pA[(24 + k * 3 + j) * 16];
                p2[j]   += r * pA[(33 + k * 3 + j) * 16];
                bc01[j] += r * pB[(6  + k * 3 + j) * 16];
                bp0[j]  += r * pB[(15 + k * 3 + j) * 16];
                bp1[j]  += r * pB[(24 + k * 3 + j) * 16];
                bp2[j]  += r * pB[(33 + k * 3 + j) * 16];
            }
        }

        const float hcs = m * (as_ + c01[0] * nh0 + c01[1] * nh1 + c01[2] * nh2);
        {
            const float cr0 = p1[1] * nh2 - p1[2] * nh1;
            const float cr1 = p1[2] * nh0 - p1[0] * nh2;
            const float cr2 = p1[0] * nh1 - p1[1] * nh0;
            const float pd  = p2[0] * nh0 + p2[1] * nh1 + p2[2] * nh2;
            const float hv0 = m * (nh0 * a10 + p0[0] + cr0 + nh0 * pd - p2[0] * third);
            const float hv1 = m * (nh1 * a10 + p0[1] + cr1 + nh1 * pd - p2[1] * third);
            const float hv2 = m * (nh2 * a10 + p0[2] + cr2 + nh2 * pd - p2[2] * third);

            const float r2s = m * (bs_ + bc01[0] * nh0 + bc01[1] * nh1 + bc01[2] * nh2);
            const float br0 = bp1[1] * nh2 - bp1[2] * nh1;
            const float br1 = bp1[2] * nh0 - bp1[0] * nh2;
            const float br2 = bp1[0] * nh1 - bp1[1] * nh0;
            const float bpd = bp2[0] * nh0 + bp2[1] * nh1 + bp2[2] * nh2;
            const float r2v0 = m * (nh0 * b10 + bp0[0] + br0 + nh0 * bpd - bp2[0] * third);
            const float r2v1 = m * (nh1 * b10 + bp0[1] + br1 + nh1 * bpd - bp2[1] * third);
            const float r2v2 = m * (nh2 * b10 + bp0[2] + br2 + nh2 * bpd - bp2[2] * third);

            const float r1s  = pA[42 * 16];
            const float r1v0 = pA[43 * 16], r1v1 = pA[44 * 16], r1v2 = pA[45 * 16];

            const float rs  = 1.0f / (1.0f + expf(-(r1s + r2s)));
            const float wv0 = r1v0 + r2v0, wv1 = r1v1 + r2v1, wv2 = r1v2 + r2v2;
            const float nn  = sqrtf(wv0 * wv0 + wv1 * wv1 + wv2 * wv2 + EPSq);
            const float sc  = (1.0f / (1.0f + expf(-nn))) / nn;
            const float rv0 = wv0 * sc, rv1 = wv1 * sc, rv2 = wv2 * sc;
            const float fs  = fabsf(rs);
            const float fv  = sqrtf(rv0 * rv0 + rv1 * rv1 + rv2 * rv2 + EPSq);

            shs += hcs;        shv0 += hv0;      shv1 += hv1;      shv2 += hv2;
            sgs += fs * hcs;   sgv0 += fv * hv0; sgv1 += fv * hv1; sgv2 += fv * hv2;
        }
    }

    // -------- reduce over 16 a-groups: shuffle within wave, LDS across waves
    float vals[8] = {shs, shv0, shv1, shv2, sgs, sgv0, sgv1, sgv2};
#pragma unroll
    for (int q = 0; q < 8; ++q) {
        vals[q] += __shfl_xor(vals[q], 16, 64);
        vals[q] += __shfl_xor(vals[q], 32, 64);
    }
    const int wave = tid >> 6;
    if ((tid & 63) < 16) {
#pragma unroll
        for (int q = 0; q < 8; ++q) redW[wave][q][u] = vals[q];
    }
    __syncthreads();

    if (tid < 16) {
        float t[8];
#pragma unroll
        for (int q = 0; q < 8; ++q)
            t[q] = redW[0][q][tid] + redW[1][q][tid] + redW[2][q][tid] + redW[3][q][tid];
        sumHs[tid] = t[0];
        sumGs[tid] = t[4];
#pragma unroll
        for (int j = 0; j < 3; ++j) {
            sumHs[16 + tid * 3 + j] = t[1 + j];
            sumGs[16 + tid * 3 + j] = t[5 + j];
        }
    }
    __syncthreads();

    // -------- epilogue: z, pre_h, new_h (16 threads)
    if (tid < 16) {
        const float* xb = x + (size_t)n * CHq * Nq + bnode;

        float zs_in = 0.f, ps_in = 0.f;
        float zv[3] = {0.f, 0.f, 0.f};
        float pv[3] = {0.f, 0.f, 0.f};
#pragma unroll
        for (int mm = 0; mm < 32; ++mm) {
            float Sh, Sg;
            if (mm < 16) { const float xv = xb[mm * Nq]; Sh = xv; Sg = xv; }
            else         { Sh = sumHs[mm - 16]; Sg = sumGs[mm - 16]; }
            zs_in += wsh[0][tid * 32 + mm] * Sh;
            ps_in += wsh[2][tid * 32 + mm] * Sg;
            const float wz = wsh[1][tid * 32 + mm];
            const float wp = wsh[3][tid * 32 + mm];
#pragma unroll
            for (int j = 0; j < 3; ++j) {
                float Vh, Vg;
                if (mm < 16) { const float xv = xb[(16 + mm * 3 + j) * Nq]; Vh = xv; Vg = xv; }
                else { Vh = sumHs[16 + (mm - 16) * 3 + j]; Vg = sumGs[16 + (mm - 16) * 3 + j]; }
                zv[j] += wz * Vh;
                pv[j] += wp * Vg;
            }
        }

        const float zs  = 1.0f / (1.0f + expf(-zs_in));
        const float zn  = sqrtf(zv[0] * zv[0] + zv[1] * zv[1] + zv[2] * zv[2] + EPSq);
        const float zsc = (1.0f / (1.0f + expf(-zn))) / zn;
        const float zv0 = zv[0] * zsc, zv1 = zv[1] * zsc, zv2 = zv[2] * zsc;
        const float phs = tanhf(ps_in);
        const float pn  = sqrtf(pv[0] * pv[0] + pv[1] * pv[1] + pv[2] * pv[2] + EPSq);
        const float psc = tanhf(pn) / pn;
        const float pv0 = pv[0] * psc, pv1 = pv[1] * psc, pv2 = pv[2] * psc;
        const float gfs = fabsf(zs);
        const float gfv = sqrtf(zv0 * zv0 + zv1 * zv1 + zv2 * zv2 + EPSq);

        float* ob = out + (size_t)n * CHq * Nq + bnode;
        const float sh_s = sumHs[tid];
        ob[tid * Nq] = sh_s + gfs * (phs + sh_s);
#pragma unroll
        for (int j = 0; j < 3; ++j) {
            const float shv = sumHs[16 + tid * 3 + j];
            const float pvj = (j == 0) ? pv0 : ((j == 1) ? pv1 : pv2);
            ob[(16 + tid * 3 + j) * Nq] = shv + gfv * (pvj + shv);
        }
    }
}

// ---------------------------------------------------------------------------
extern "C" void kernel_launch(void* const* d_in, const int* in_sizes, int n_in,
                              void* d_out, int out_size, void* d_ws, size_t ws_size,
                              hipStream_t stream) {
    const float* x      = (const float*)d_in[0];
    const float* h_nei  = (const float*)d_in[1];
    const float* hdiff  = (const float*)d_in[2];
    const float* mask   = (const float*)d_in[3];
    const float* w00    = (const float*)d_in[4];
    const float* w10    = (const float*)d_in[5];
    const float* w01    = (const float*)d_in[6];
    const float* w11    = (const float*)d_in[7];
    const float* wz0    = (const float*)d_in[8];
    const float* wz1    = (const float*)d_in[9];
    const float* wr10   = (const float*)d_in[10];
    const float* wr11   = (const float*)d_in[11];
    const float* wr20   = (const float*)d_in[12];
    const float* wr21   = (const float*)d_in[13];
    const float* wp0    = (const float*)d_in[14];
    const float* wp1    = (const float*)d_in[15];
    float* out = (float*)d_out;

    char* ws = (char*)d_ws;
    float*    pcA = (float*)ws;                          // 320*46*16*4 = 942,080 B
    float*    pcB = (float*)(ws + (1 << 20));            // 320*42*16*4 = 860,160 B
    unsigned* bar = (unsigned*)(ws + (2 << 20));         // 4 KB of counters

    hipMemsetAsync(bar, 0, 4096, stream);
    se3_fused<<<NBLK, 256, 0, stream>>>(
        x, h_nei, hdiff, mask, w00, w10, w01, w11,
        wr10, wr11, wr20, wr21, wz0, wz1, wp0, wp1,
        pcA, pcB, bar, out);
}

// Round 4
// 46.083 us; speedup vs baseline: 1.5429x; 1.5429x over previous
//
#include <hip/hip_runtime.h>
#include <math.h>

// Problem constants (match reference)
#define Bq 4
#define Nq 80
#define CHq 64
#define GAMMAq 4.0f
#define EPSq 1e-6f
#define PCW 96       // padded floats per (na,u) row in pc
#define PCWL 100     // LDS row pad (avoid 32-bank stride)

// Packed comp map within pc[na][u][0..95]:
//   0-2   A00[k]        3-5   A10[k]       6-14  C01[k][j]
//   15-23 P0[k][j]      24-32 P1[k][j]     33-41 P2[k][j]
//   42 r1s  43-45 r1v   46-47 pad
//   48+c (c=0..41): wr2-mixed copies of comps 0..41 (r2 fold)   90-95 pad

// ---------------------------------------------------------------------------
// Kernel 1: block per na (320 blocks, 64 threads).
//  stage 1: cooperative load of h_nei[n][:][a], x[n][:][a] into LDS (2 ld/thr)
//  stage 2: thread (u = t&15, kk = t>>4): kk<3 -> k-slice contractions;
//           kk==3 -> r1 = SI(x) row + pad zeroing
//  stage 3: pcB fold (r2 = SI(h_conv) commuted into the pair contraction)
//  stage 4: coalesced float4 write of the packed [u][96] block
// ---------------------------------------------------------------------------
__global__ __launch_bounds__(64) void se3_precomp(
    const float* __restrict__ h_nei,   // [B][CH][N]
    const float* __restrict__ x,       // [B][CH][N]
    const float* __restrict__ w00,     // [M][M][3]
    const float* __restrict__ w10,
    const float* __restrict__ w01,
    const float* __restrict__ w11,     // [3][M][M][3]
    const float* __restrict__ wr10,    // [M][M]
    const float* __restrict__ wr11,
    const float* __restrict__ wr20,    // [M][M]
    const float* __restrict__ wr21,
    float* __restrict__ pc)
{
    const int na = blockIdx.x;                 // 0..319
    const int n  = na / Nq, a = na - n * Nq;
    const int t  = threadIdx.x;                // 0..63
    const int u  = t & 15;
    const int kk = t >> 4;                     // 0..3

    __shared__ float hsh[64];
    __shared__ float xsh[64];
    __shared__ float pout[16][PCWL];           // [u][comp], padded rows

    hsh[t] = h_nei[(size_t)n * CHq * Nq + t * Nq + a];
    xsh[t] = x    [(size_t)n * CHq * Nq + t * Nq + a];
    __syncthreads();

    if (kk < 3) {
        const int k = kk;
        float a00 = 0.f, a10 = 0.f;
        float c[3] = {0.f,0.f,0.f}, p0[3] = {0.f,0.f,0.f};
        float p1[3] = {0.f,0.f,0.f}, p2[3] = {0.f,0.f,0.f};
#pragma unroll
        for (int v = 0; v < 16; ++v) {
            const float s = hsh[v];
            a00 += w00[(u * 16 + v) * 3 + k] * s;
            a10 += w10[(u * 16 + v) * 3 + k] * s;
            const float w01v = w01[(u * 16 + v) * 3 + k];
            const float w110 = w11[((0 * 16 + u) * 16 + v) * 3 + k];
            const float w111 = w11[((1 * 16 + u) * 16 + v) * 3 + k];
            const float w112 = w11[((2 * 16 + u) * 16 + v) * 3 + k];
#pragma unroll
            for (int j = 0; j < 3; ++j) {
                const float Vj = hsh[16 + v * 3 + j];
                c[j]  += w01v * Vj;
                p0[j] += w110 * Vj;
                p1[j] += w111 * Vj;
                p2[j] += w112 * Vj;
            }
        }
        pout[u][0 + k] = a00;
        pout[u][3 + k] = a10;
#pragma unroll
        for (int j = 0; j < 3; ++j) {
            pout[u][6  + k * 3 + j] = c[j];
            pout[u][15 + k * 3 + j] = p0[j];
            pout[u][24 + k * 3 + j] = p1[j];
            pout[u][33 + k * 3 + j] = p2[j];
        }
    } else {
        // r1 = SI(x) for this u
        float r1s = 0.f, r1v[3] = {0.f, 0.f, 0.f};
#pragma unroll
        for (int v = 0; v < 16; ++v) {
            r1s += wr10[u * 16 + v] * xsh[v];
            const float wv = wr11[u * 16 + v];
#pragma unroll
            for (int j = 0; j < 3; ++j) r1v[j] += wv * xsh[16 + v * 3 + j];
        }
        pout[u][42] = r1s;
#pragma unroll
        for (int j = 0; j < 3; ++j) pout[u][43 + j] = r1v[j];
        // pads
        pout[u][46] = 0.f; pout[u][47] = 0.f;
#pragma unroll
        for (int j = 90; j < 96; ++j) pout[u][j] = 0.f;
    }
    __syncthreads();

    // stage 3: B[u][c] = sum_v wr2[u][v] * A[v][c]   (c = kk, kk+4, ..., <42)
    for (int c = kk; c < 42; c += 4) {
        const bool scalarType = (c < 3) || (c >= 6 && c < 15);
        const float* W = scalarType ? wr20 : wr21;
        float acc = 0.f;
#pragma unroll
        for (int v = 0; v < 16; ++v) acc += W[u * 16 + v] * pout[v][c];
        pout[u][48 + c] = acc;   // write region disjoint from read region
    }
    __syncthreads();

    // stage 4: coalesced write-out. thread t: row r = t>>2, quarter q = t&3.
    {
        const int r = t >> 2, q = t & 3;
        const float4* src = reinterpret_cast<const float4*>(&pout[r][q * 24]);
        float4* dst = reinterpret_cast<float4*>(pc + (size_t)na * 16 * PCW + r * PCW + q * 24);
#pragma unroll
        for (int i = 0; i < 6; ++i) dst[i] = src[i];
    }
}

// ---------------------------------------------------------------------------
// Kernel 2: block per (n,b) (320 blocks, 256 threads = 16 a-groups x 16 u).
// Barrier-free a-loop: per pair, 23 float4 loads of packed pc row,
// h_conv + folded r2 + gate entirely thread-local; shuffle-reduce; epilogue.
// ---------------------------------------------------------------------------
__global__ __launch_bounds__(256) void se3_main(
    const float* __restrict__ x,       // [B][CH][N]
    const float* __restrict__ hdiff,   // [B][N][N][3]
    const float* __restrict__ mask,    // [B][N][N]
    const float* __restrict__ wz0,     // [M][2M]
    const float* __restrict__ wz1,
    const float* __restrict__ wp0,
    const float* __restrict__ wp1,
    const float* __restrict__ pc,
    float* __restrict__ out)           // [B][CH][N]
{
    const int nb    = blockIdx.x;      // 0..319
    const int n     = nb / Nq;
    const int bnode = nb - n * Nq;
    const int tid   = threadIdx.x;
    const int g     = tid >> 4;        // a-group 0..15
    const int u     = tid & 15;        // channel 0..15

    __shared__ float wsh[4][512];      // wz0, wz1, wp0, wp1
    __shared__ float redW[4][8][16];
    __shared__ float sumHs[64], sumGs[64];

#pragma unroll
    for (int i = 0; i < 2; ++i) {
        const int idx = tid + i * 256;
        wsh[0][idx] = wz0[idx];
        wsh[1][idx] = wz1[idx];
        wsh[2][idx] = wp0[idx];
        wsh[3][idx] = wp1[idx];
    }

    float shs = 0.f, shv0 = 0.f, shv1 = 0.f, shv2 = 0.f;
    float sgs = 0.f, sgv0 = 0.f, sgv1 = 0.f, sgv2 = 0.f;

    const float* drow = hdiff + (size_t)(n * Nq + bnode) * Nq * 3;
    const float* mrow = mask  + (size_t)(n * Nq + bnode) * Nq;
    const float third = 1.0f / 3.0f;

    for (int it = 0; it < 5; ++it) {
        const int a = it * 16 + g;

        const float d0 = drow[a * 3 + 0], d1 = drow[a * 3 + 1], d2 = drow[a * 3 + 2];
        const float m  = mrow[a];

        const float rad = sqrtf(d0 * d0 + d1 * d1 + d2 * d2 + EPSq);
        const float inv = 1.0f / rad;
        const float nh0 = d0 * inv, nh1 = d1 * inv, nh2 = d2 * inv;
        float rb[3];
        rb[0] = expf(-GAMMAq * rad * rad);
        { float t1 = rad - 0.5f; rb[1] = expf(-GAMMAq * t1 * t1); }
        { float t2 = rad - 1.0f; rb[2] = expf(-GAMMAq * t2 * t2); }

        const float4* p4 = reinterpret_cast<const float4*>(
            pc + ((size_t)(n * Nq + a) * 16 + u) * PCW);

        float pa[48];
#pragma unroll
        for (int i = 0; i < 12; ++i)
            *reinterpret_cast<float4*>(&pa[i * 4]) = p4[i];
        float pb[44];
#pragma unroll
        for (int i = 0; i < 11; ++i)
            *reinterpret_cast<float4*>(&pb[i * 4]) = p4[12 + i];

        float as_ = 0.f, a10 = 0.f;
        float c01[3] = {0.f,0.f,0.f}, p0[3] = {0.f,0.f,0.f};
        float p1[3] = {0.f,0.f,0.f}, p2[3] = {0.f,0.f,0.f};
        float bs_ = 0.f, b10 = 0.f;
        float bc01[3] = {0.f,0.f,0.f}, bp0[3] = {0.f,0.f,0.f};
        float bp1[3] = {0.f,0.f,0.f}, bp2[3] = {0.f,0.f,0.f};
#pragma unroll
        for (int k = 0; k < 3; ++k) {
            const float r = rb[k];
            as_ += r * pa[0 + k];
            a10 += r * pa[3 + k];
            bs_ += r * pb[0 + k];
            b10 += r * pb[3 + k];
#pragma unroll
            for (int j = 0; j < 3; ++j) {
                c01[j]  += r * pa[6  + k * 3 + j];
                p0[j]   += r * pa[15 + k * 3 + j];
                p1[j]   += r * pa[24 + k * 3 + j];
                p2[j]   += r * pa[33 + k * 3 + j];
                bc01[j] += r * pb[6  + k * 3 + j];
                bp0[j]  += r * pb[15 + k * 3 + j];
                bp1[j]  += r * pb[24 + k * 3 + j];
                bp2[j]  += r * pb[33 + k * 3 + j];
            }
        }

        const float hcs = m * (as_ + c01[0] * nh0 + c01[1] * nh1 + c01[2] * nh2);
        const float cr0 = p1[1] * nh2 - p1[2] * nh1;
        const float cr1 = p1[2] * nh0 - p1[0] * nh2;
        const float cr2 = p1[0] * nh1 - p1[1] * nh0;
        const float pd  = p2[0] * nh0 + p2[1] * nh1 + p2[2] * nh2;
        const float hv0 = m * (nh0 * a10 + p0[0] + cr0 + nh0 * pd - p2[0] * third);
        const float hv1 = m * (nh1 * a10 + p0[1] + cr1 + nh1 * pd - p2[1] * third);
        const float hv2 = m * (nh2 * a10 + p0[2] + cr2 + nh2 * pd - p2[2] * third);

        const float r2s = m * (bs_ + bc01[0] * nh0 + bc01[1] * nh1 + bc01[2] * nh2);
        const float br0 = bp1[1] * nh2 - bp1[2] * nh1;
        const float br1 = bp1[2] * nh0 - bp1[0] * nh2;
        const float br2 = bp1[0] * nh1 - bp1[1] * nh0;
        const float bpd = bp2[0] * nh0 + bp2[1] * nh1 + bp2[2] * nh2;
        const float r2v0 = m * (nh0 * b10 + bp0[0] + br0 + nh0 * bpd - bp2[0] * third);
        const float r2v1 = m * (nh1 * b10 + bp0[1] + br1 + nh1 * bpd - bp2[1] * third);
        const float r2v2 = m * (nh2 * b10 + bp0[2] + br2 + nh2 * bpd - bp2[2] * third);

        const float r1s  = pa[42];
        const float r1v0 = pa[43], r1v1 = pa[44], r1v2 = pa[45];

        const float rs  = 1.0f / (1.0f + expf(-(r1s + r2s)));
        const float wv0 = r1v0 + r2v0, wv1 = r1v1 + r2v1, wv2 = r1v2 + r2v2;
        const float nn  = sqrtf(wv0 * wv0 + wv1 * wv1 + wv2 * wv2 + EPSq);
        const float sc  = (1.0f / (1.0f + expf(-nn))) / nn;
        const float rv0 = wv0 * sc, rv1 = wv1 * sc, rv2 = wv2 * sc;
        const float fs  = fabsf(rs);
        const float fv  = sqrtf(rv0 * rv0 + rv1 * rv1 + rv2 * rv2 + EPSq);

        shs += hcs;        shv0 += hv0;      shv1 += hv1;      shv2 += hv2;
        sgs += fs * hcs;   sgv0 += fv * hv0; sgv1 += fv * hv1; sgv2 += fv * hv2;
    }

    // -------- reduce over 16 a-groups: shuffle within wave, LDS across waves
    float vals[8] = {shs, shv0, shv1, shv2, sgs, sgv0, sgv1, sgv2};
#pragma unroll
    for (int q = 0; q < 8; ++q) {
        vals[q] += __shfl_xor(vals[q], 16, 64);
        vals[q] += __shfl_xor(vals[q], 32, 64);
    }
    const int wave = tid >> 6;
    if ((tid & 63) < 16) {
#pragma unroll
        for (int q = 0; q < 8; ++q) redW[wave][q][u] = vals[q];
    }
    __syncthreads();

    if (tid < 16) {
        float tacc[8];
#pragma unroll
        for (int q = 0; q < 8; ++q)
            tacc[q] = redW[0][q][tid] + redW[1][q][tid] + redW[2][q][tid] + redW[3][q][tid];
        sumHs[tid] = tacc[0];
        sumGs[tid] = tacc[4];
#pragma unroll
        for (int j = 0; j < 3; ++j) {
            sumHs[16 + tid * 3 + j] = tacc[1 + j];
            sumGs[16 + tid * 3 + j] = tacc[5 + j];
        }
    }
    __syncthreads();

    // -------- epilogue: z, pre_h, new_h (16 threads)
    if (tid < 16) {
        const float* xb = x + (size_t)n * CHq * Nq + bnode;

        float zs_in = 0.f, ps_in = 0.f;
        float zv[3] = {0.f, 0.f, 0.f};
        float pv[3] = {0.f, 0.f, 0.f};
#pragma unroll
        for (int mm = 0; mm < 32; ++mm) {
            float Sh, Sg;
            if (mm < 16) { const float xv = xb[mm * Nq]; Sh = xv; Sg = xv; }
            else         { Sh = sumHs[mm - 16]; Sg = sumGs[mm - 16]; }
            zs_in += wsh[0][tid * 32 + mm] * Sh;
            ps_in += wsh[2][tid * 32 + mm] * Sg;
            const float wz = wsh[1][tid * 32 + mm];
            const float wp = wsh[3][tid * 32 + mm];
#pragma unroll
            for (int j = 0; j < 3; ++j) {
                float Vh, Vg;
                if (mm < 16) { const float xv = xb[(16 + mm * 3 + j) * Nq]; Vh = xv; Vg = xv; }
                else { Vh = sumHs[16 + (mm - 16) * 3 + j]; Vg = sumGs[16 + (mm - 16) * 3 + j]; }
                zv[j] += wz * Vh;
                pv[j] += wp * Vg;
            }
        }

        const float zs  = 1.0f / (1.0f + expf(-zs_in));
        const float zn  = sqrtf(zv[0] * zv[0] + zv[1] * zv[1] + zv[2] * zv[2] + EPSq);
        const float zsc = (1.0f / (1.0f + expf(-zn))) / zn;
        const float zv0 = zv[0] * zsc, zv1 = zv[1] * zsc, zv2 = zv[2] * zsc;
        const float phs = tanhf(ps_in);
        const float pn  = sqrtf(pv[0] * pv[0] + pv[1] * pv[1] + pv[2] * pv[2] + EPSq);
        const float psc = tanhf(pn) / pn;
        const float pv0 = pv[0] * psc, pv1 = pv[1] * psc, pv2 = pv[2] * psc;
        const float gfs = fabsf(zs);
        const float gfv = sqrtf(zv0 * zv0 + zv1 * zv1 + zv2 * zv2 + EPSq);

        float* ob = out + (size_t)n * CHq * Nq + bnode;
        const float sh_s = sumHs[tid];
        ob[tid * Nq] = sh_s + gfs * (phs + sh_s);
#pragma unroll
        for (int j = 0; j < 3; ++j) {
            const float shv = sumHs[16 + tid * 3 + j];
            const float pvj = (j == 0) ? pv0 : ((j == 1) ? pv1 : pv2);
            ob[(16 + tid * 3 + j) * Nq] = shv + gfv * (pvj + shv);
        }
    }
}

// ---------------------------------------------------------------------------
extern "C" void kernel_launch(void* const* d_in, const int* in_sizes, int n_in,
                              void* d_out, int out_size, void* d_ws, size_t ws_size,
                              hipStream_t stream) {
    const float* x      = (const float*)d_in[0];
    const float* h_nei  = (const float*)d_in[1];
    const float* hdiff  = (const float*)d_in[2];
    const float* mask   = (const float*)d_in[3];
    const float* w00    = (const float*)d_in[4];
    const float* w10    = (const float*)d_in[5];
    const float* w01    = (const float*)d_in[6];
    const float* w11    = (const float*)d_in[7];
    const float* wz0    = (const float*)d_in[8];
    const float* wz1    = (const float*)d_in[9];
    const float* wr10   = (const float*)d_in[10];
    const float* wr11   = (const float*)d_in[11];
    const float* wr20   = (const float*)d_in[12];
    const float* wr21   = (const float*)d_in[13];
    const float* wp0    = (const float*)d_in[14];
    const float* wp1    = (const float*)d_in[15];
    float* out = (float*)d_out;
    float* pc  = (float*)d_ws;   // 320 * 16 * 96 * 4 = 1,966,080 bytes

    se3_precomp<<<Bq * Nq, 64, 0, stream>>>(
        h_nei, x, w00, w10, w01, w11, wr10, wr11, wr20, wr21, pc);
    se3_main<<<Bq * Nq, 256, 0, stream>>>(
        x, hdiff, mask, wz0, wz1, wp0, wp1, pc, out);
}

// Round 5
// 27.691 us; speedup vs baseline: 2.5677x; 1.6642x over previous
//
#include <hip/hip_runtime.h>
#include <math.h>

// Problem constants (match reference)
#define Bq 4
#define Nq 80
#define CHq 64
#define GAMMAq 4.0f
#define EPSq 1e-6f
#define PCWL 100     // LDS row pad (avoid 32-bank stride)
#define NQUAD 24     // float4 quads per (na,u): 96 floats

// Packed comp map (per (na,u), 96 floats, stored as quads interleaved by u):
//   0-2   A00[k]        3-5   A10[k]       6-14  C01[k][j]
//   15-23 P0[k][j]      24-32 P1[k][j]     33-41 P2[k][j]
//   42 r1s  43-45 r1v   46-47 pad
//   48+c (c=0..41): wr2-mixed copies of comps 0..41 (r2 fold)   90-95 pad
// Global layout: pc_quad[ na ][ c4 0..23 ][ u 0..15 ]  (float4 each)
//   -> 16 u-lanes read 256B contiguous per quad: fully coalesced.

// ---------------------------------------------------------------------------
// Kernel 1: block per na (320 blocks, 64 threads).
//  stage 1: cooperative load of h_nei[n][:][a], x[n][:][a] into LDS (2 ld/thr)
//  stage 2: thread (u = t&15, kk = t>>4): kk<3 -> k-slice contractions;
//           kk==3 -> r1 = SI(x) row + pad zeroing
//  stage 3: r2 fold: B[u][c] = sum_v wr2[u][v] * A[v][c]
//  stage 4: coalesced interleaved quad write-out
// ---------------------------------------------------------------------------
__global__ __launch_bounds__(64) void se3_precomp(
    const float* __restrict__ h_nei,   // [B][CH][N]
    const float* __restrict__ x,       // [B][CH][N]
    const float* __restrict__ w00,     // [M][M][3]
    const float* __restrict__ w10,
    const float* __restrict__ w01,
    const float* __restrict__ w11,     // [3][M][M][3]
    const float* __restrict__ wr10,    // [M][M]
    const float* __restrict__ wr11,
    const float* __restrict__ wr20,    // [M][M]
    const float* __restrict__ wr21,
    float* __restrict__ pc)
{
    const int na = blockIdx.x;                 // 0..319
    const int n  = na / Nq, a = na - n * Nq;
    const int t  = threadIdx.x;                // 0..63
    const int u  = t & 15;
    const int kk = t >> 4;                     // 0..3

    __shared__ float hsh[64];
    __shared__ float xsh[64];
    __shared__ float pout[16][PCWL];           // [u][comp], padded rows

    hsh[t] = h_nei[(size_t)n * CHq * Nq + t * Nq + a];
    xsh[t] = x    [(size_t)n * CHq * Nq + t * Nq + a];
    __syncthreads();

    if (kk < 3) {
        const int k = kk;
        float a00 = 0.f, a10 = 0.f;
        float c[3] = {0.f,0.f,0.f}, p0[3] = {0.f,0.f,0.f};
        float p1[3] = {0.f,0.f,0.f}, p2[3] = {0.f,0.f,0.f};
#pragma unroll
        for (int v = 0; v < 16; ++v) {
            const float s = hsh[v];
            a00 += w00[(u * 16 + v) * 3 + k] * s;
            a10 += w10[(u * 16 + v) * 3 + k] * s;
            const float w01v = w01[(u * 16 + v) * 3 + k];
            const float w110 = w11[((0 * 16 + u) * 16 + v) * 3 + k];
            const float w111 = w11[((1 * 16 + u) * 16 + v) * 3 + k];
            const float w112 = w11[((2 * 16 + u) * 16 + v) * 3 + k];
#pragma unroll
            for (int j = 0; j < 3; ++j) {
                const float Vj = hsh[16 + v * 3 + j];
                c[j]  += w01v * Vj;
                p0[j] += w110 * Vj;
                p1[j] += w111 * Vj;
                p2[j] += w112 * Vj;
            }
        }
        pout[u][0 + k] = a00;
        pout[u][3 + k] = a10;
#pragma unroll
        for (int j = 0; j < 3; ++j) {
            pout[u][6  + k * 3 + j] = c[j];
            pout[u][15 + k * 3 + j] = p0[j];
            pout[u][24 + k * 3 + j] = p1[j];
            pout[u][33 + k * 3 + j] = p2[j];
        }
    } else {
        // r1 = SI(x) for this u
        float r1s = 0.f, r1v[3] = {0.f, 0.f, 0.f};
#pragma unroll
        for (int v = 0; v < 16; ++v) {
            r1s += wr10[u * 16 + v] * xsh[v];
            const float wv = wr11[u * 16 + v];
#pragma unroll
            for (int j = 0; j < 3; ++j) r1v[j] += wv * xsh[16 + v * 3 + j];
        }
        pout[u][42] = r1s;
#pragma unroll
        for (int j = 0; j < 3; ++j) pout[u][43 + j] = r1v[j];
        // pads
        pout[u][46] = 0.f; pout[u][47] = 0.f;
#pragma unroll
        for (int j = 90; j < 96; ++j) pout[u][j] = 0.f;
    }
    __syncthreads();

    // stage 3: B[u][c] = sum_v wr2[u][v] * A[v][c]   (c = kk, kk+4, ..., <42)
    for (int c = kk; c < 42; c += 4) {
        const bool scalarType = (c < 3) || (c >= 6 && c < 15);
        const float* W = scalarType ? wr20 : wr21;
        float acc = 0.f;
#pragma unroll
        for (int v = 0; v < 16; ++v) acc += W[u * 16 + v] * pout[v][c];
        pout[u][48 + c] = acc;   // write region disjoint from read region
    }
    __syncthreads();

    // stage 4: interleaved quad write. thread (u,kk) writes quads kk, kk+4, ...
    {
        float4* dst = reinterpret_cast<float4*>(pc) + (size_t)na * (NQUAD * 16) + u;
#pragma unroll
        for (int i = 0; i < 6; ++i) {
            const int c4 = kk + i * 4;
            dst[c4 * 16] = make_float4(pout[u][c4 * 4 + 0], pout[u][c4 * 4 + 1],
                                       pout[u][c4 * 4 + 2], pout[u][c4 * 4 + 3]);
        }
    }
}

// ---------------------------------------------------------------------------
// Kernel 2: block per (n,b) (320 blocks, 256 threads = 16 a-groups x 16 u).
// Barrier-free a-loop: per pair, 23 fully-coalesced float4 loads,
// h_conv + folded r2 + gate entirely thread-local; shuffle-reduce; epilogue.
// ---------------------------------------------------------------------------
__global__ __launch_bounds__(256) void se3_main(
    const float* __restrict__ x,       // [B][CH][N]
    const float* __restrict__ hdiff,   // [B][N][N][3]
    const float* __restrict__ mask,    // [B][N][N]
    const float* __restrict__ wz0,     // [M][2M]
    const float* __restrict__ wz1,
    const float* __restrict__ wp0,
    const float* __restrict__ wp1,
    const float* __restrict__ pc,
    float* __restrict__ out)           // [B][CH][N]
{
    const int nb    = blockIdx.x;      // 0..319
    const int n     = nb / Nq;
    const int bnode = nb - n * Nq;
    const int tid   = threadIdx.x;
    const int g     = tid >> 4;        // a-group 0..15
    const int u     = tid & 15;        // channel 0..15

    __shared__ float wsh[4][512];      // wz0, wz1, wp0, wp1
    __shared__ float redW[4][8][16];
    __shared__ float sumHs[64], sumGs[64];

#pragma unroll
    for (int i = 0; i < 2; ++i) {
        const int idx = tid + i * 256;
        wsh[0][idx] = wz0[idx];
        wsh[1][idx] = wz1[idx];
        wsh[2][idx] = wp0[idx];
        wsh[3][idx] = wp1[idx];
    }

    float shs = 0.f, shv0 = 0.f, shv1 = 0.f, shv2 = 0.f;
    float sgs = 0.f, sgv0 = 0.f, sgv1 = 0.f, sgv2 = 0.f;

    const float* drow = hdiff + (size_t)(n * Nq + bnode) * Nq * 3;
    const float* mrow = mask  + (size_t)(n * Nq + bnode) * Nq;
    const float third = 1.0f / 3.0f;

    for (int it = 0; it < 5; ++it) {
        const int a = it * 16 + g;

        const float d0 = drow[a * 3 + 0], d1 = drow[a * 3 + 1], d2 = drow[a * 3 + 2];
        const float m  = mrow[a];

        const float rad = sqrtf(d0 * d0 + d1 * d1 + d2 * d2 + EPSq);
        const float inv = 1.0f / rad;
        const float nh0 = d0 * inv, nh1 = d1 * inv, nh2 = d2 * inv;
        float rb[3];
        rb[0] = expf(-GAMMAq * rad * rad);
        { float t1 = rad - 0.5f; rb[1] = expf(-GAMMAq * t1 * t1); }
        { float t2 = rad - 1.0f; rb[2] = expf(-GAMMAq * t2 * t2); }

        // quad-interleaved, u-coalesced reads
        const float4* p4 = reinterpret_cast<const float4*>(pc)
                         + (size_t)(n * Nq + a) * (NQUAD * 16) + u;

        float pa[48];
#pragma unroll
        for (int i = 0; i < 12; ++i)
            *reinterpret_cast<float4*>(&pa[i * 4]) = p4[i * 16];
        float pb[44];
#pragma unroll
        for (int i = 0; i < 11; ++i)
            *reinterpret_cast<float4*>(&pb[i * 4]) = p4[(12 + i) * 16];

        float as_ = 0.f, a10 = 0.f;
        float c01[3] = {0.f,0.f,0.f}, p0[3] = {0.f,0.f,0.f};
        float p1[3] = {0.f,0.f,0.f}, p2[3] = {0.f,0.f,0.f};
        float bs_ = 0.f, b10 = 0.f;
        float bc01[3] = {0.f,0.f,0.f}, bp0[3] = {0.f,0.f,0.f};
        float bp1[3] = {0.f,0.f,0.f}, bp2[3] = {0.f,0.f,0.f};
#pragma unroll
        for (int k = 0; k < 3; ++k) {
            const float r = rb[k];
            as_ += r * pa[0 + k];
            a10 += r * pa[3 + k];
            bs_ += r * pb[0 + k];
            b10 += r * pb[3 + k];
#pragma unroll
            for (int j = 0; j < 3; ++j) {
                c01[j]  += r * pa[6  + k * 3 + j];
                p0[j]   += r * pa[15 + k * 3 + j];
                p1[j]   += r * pa[24 + k * 3 + j];
                p2[j]   += r * pa[33 + k * 3 + j];
                bc01[j] += r * pb[6  + k * 3 + j];
                bp0[j]  += r * pb[15 + k * 3 + j];
                bp1[j]  += r * pb[24 + k * 3 + j];
                bp2[j]  += r * pb[33 + k * 3 + j];
            }
        }

        const float hcs = m * (as_ + c01[0] * nh0 + c01[1] * nh1 + c01[2] * nh2);
        const float cr0 = p1[1] * nh2 - p1[2] * nh1;
        const float cr1 = p1[2] * nh0 - p1[0] * nh2;
        const float cr2 = p1[0] * nh1 - p1[1] * nh0;
        const float pd  = p2[0] * nh0 + p2[1] * nh1 + p2[2] * nh2;
        const float hv0 = m * (nh0 * a10 + p0[0] + cr0 + nh0 * pd - p2[0] * third);
        const float hv1 = m * (nh1 * a10 + p0[1] + cr1 + nh1 * pd - p2[1] * third);
        const float hv2 = m * (nh2 * a10 + p0[2] + cr2 + nh2 * pd - p2[2] * third);

        const float r2s = m * (bs_ + bc01[0] * nh0 + bc01[1] * nh1 + bc01[2] * nh2);
        const float br0 = bp1[1] * nh2 - bp1[2] * nh1;
        const float br1 = bp1[2] * nh0 - bp1[0] * nh2;
        const float br2 = bp1[0] * nh1 - bp1[1] * nh0;
        const float bpd = bp2[0] * nh0 + bp2[1] * nh1 + bp2[2] * nh2;
        const float r2v0 = m * (nh0 * b10 + bp0[0] + br0 + nh0 * bpd - bp2[0] * third);
        const float r2v1 = m * (nh1 * b10 + bp0[1] + br1 + nh1 * bpd - bp2[1] * third);
        const float r2v2 = m * (nh2 * b10 + bp0[2] + br2 + nh2 * bpd - bp2[2] * third);

        const float r1s  = pa[42];
        const float r1v0 = pa[43], r1v1 = pa[44], r1v2 = pa[45];

        const float rs  = 1.0f / (1.0f + expf(-(r1s + r2s)));
        const float wv0 = r1v0 + r2v0, wv1 = r1v1 + r2v1, wv2 = r1v2 + r2v2;
        const float nn  = sqrtf(wv0 * wv0 + wv1 * wv1 + wv2 * wv2 + EPSq);
        const float sc  = (1.0f / (1.0f + expf(-nn))) / nn;
        const float rv0 = wv0 * sc, rv1 = wv1 * sc, rv2 = wv2 * sc;
        const float fs  = fabsf(rs);
        const float fv  = sqrtf(rv0 * rv0 + rv1 * rv1 + rv2 * rv2 + EPSq);

        shs += hcs;        shv0 += hv0;      shv1 += hv1;      shv2 += hv2;
        sgs += fs * hcs;   sgv0 += fv * hv0; sgv1 += fv * hv1; sgv2 += fv * hv2;
    }

    // -------- reduce over 16 a-groups: shuffle within wave, LDS across waves
    float vals[8] = {shs, shv0, shv1, shv2, sgs, sgv0, sgv1, sgv2};
#pragma unroll
    for (int q = 0; q < 8; ++q) {
        vals[q] += __shfl_xor(vals[q], 16, 64);
        vals[q] += __shfl_xor(vals[q], 32, 64);
    }
    const int wave = tid >> 6;
    if ((tid & 63) < 16) {
#pragma unroll
        for (int q = 0; q < 8; ++q) redW[wave][q][u] = vals[q];
    }
    __syncthreads();

    if (tid < 16) {
        float tacc[8];
#pragma unroll
        for (int q = 0; q < 8; ++q)
            tacc[q] = redW[0][q][tid] + redW[1][q][tid] + redW[2][q][tid] + redW[3][q][tid];
        sumHs[tid] = tacc[0];
        sumGs[tid] = tacc[4];
#pragma unroll
        for (int j = 0; j < 3; ++j) {
            sumHs[16 + tid * 3 + j] = tacc[1 + j];
            sumGs[16 + tid * 3 + j] = tacc[5 + j];
        }
    }
    __syncthreads();

    // -------- epilogue: z, pre_h, new_h (16 threads)
    if (tid < 16) {
        const float* xb = x + (size_t)n * CHq * Nq + bnode;

        float zs_in = 0.f, ps_in = 0.f;
        float zv[3] = {0.f, 0.f, 0.f};
        float pv[3] = {0.f, 0.f, 0.f};
#pragma unroll
        for (int mm = 0; mm < 32; ++mm) {
            float Sh, Sg;
            if (mm < 16) { const float xv = xb[mm * Nq]; Sh = xv; Sg = xv; }
            else         { Sh = sumHs[mm - 16]; Sg = sumGs[mm - 16]; }
            zs_in += wsh[0][tid * 32 + mm] * Sh;
            ps_in += wsh[2][tid * 32 + mm] * Sg;
            const float wz = wsh[1][tid * 32 + mm];
            const float wp = wsh[3][tid * 32 + mm];
#pragma unroll
            for (int j = 0; j < 3; ++j) {
                float Vh, Vg;
                if (mm < 16) { const float xv = xb[(16 + mm * 3 + j) * Nq]; Vh = xv; Vg = xv; }
                else { Vh = sumHs[16 + (mm - 16) * 3 + j]; Vg = sumGs[16 + (mm - 16) * 3 + j]; }
                zv[j] += wz * Vh;
                pv[j] += wp * Vg;
            }
        }

        const float zs  = 1.0f / (1.0f + expf(-zs_in));
        const float zn  = sqrtf(zv[0] * zv[0] + zv[1] * zv[1] + zv[2] * zv[2] + EPSq);
        const float zsc = (1.0f / (1.0f + expf(-zn))) / zn;
        const float zv0 = zv[0] * zsc, zv1 = zv[1] * zsc, zv2 = zv[2] * zsc;
        const float phs = tanhf(ps_in);
        const float pn  = sqrtf(pv[0] * pv[0] + pv[1] * pv[1] + pv[2] * pv[2] + EPSq);
        const float psc = tanhf(pn) / pn;
        const float pv0 = pv[0] * psc, pv1 = pv[1] * psc, pv2 = pv[2] * psc;
        const float gfs = fabsf(zs);
        const float gfv = sqrtf(zv0 * zv0 + zv1 * zv1 + zv2 * zv2 + EPSq);

        float* ob = out + (size_t)n * CHq * Nq + bnode;
        const float sh_s = sumHs[tid];
        ob[tid * Nq] = sh_s + gfs * (phs + sh_s);
#pragma unroll
        for (int j = 0; j < 3; ++j) {
            const float shv = sumHs[16 + tid * 3 + j];
            const float pvj = (j == 0) ? pv0 : ((j == 1) ? pv1 : pv2);
            ob[(16 + tid * 3 + j) * Nq] = shv + gfv * (pvj + shv);
        }
    }
}

// ---------------------------------------------------------------------------
extern "C" void kernel_launch(void* const* d_in, const int* in_sizes, int n_in,
                              void* d_out, int out_size, void* d_ws, size_t ws_size,
                              hipStream_t stream) {
    const float* x      = (const float*)d_in[0];
    const float* h_nei  = (const float*)d_in[1];
    const float* hdiff  = (const float*)d_in[2];
    const float* mask   = (const float*)d_in[3];
    const float* w00    = (const float*)d_in[4];
    const float* w10    = (const float*)d_in[5];
    const float* w01    = (const float*)d_in[6];
    const float* w11    = (const float*)d_in[7];
    const float* wz0    = (const float*)d_in[8];
    const float* wz1    = (const float*)d_in[9];
    const float* wr10   = (const float*)d_in[10];
    const float* wr11   = (const float*)d_in[11];
    const float* wr20   = (const float*)d_in[12];
    const float* wr21   = (const float*)d_in[13];
    const float* wp0    = (const float*)d_in[14];
    const float* wp1    = (const float*)d_in[15];
    float* out = (float*)d_out;
    float* pc  = (float*)d_ws;   // 320 * 24 * 16 * 16 B = 1,966,080 bytes

    se3_precomp<<<Bq * Nq, 64, 0, stream>>>(
        h_nei, x, w00, w10, w01, w11, wr10, wr11, wr20, wr21, pc);
    se3_main<<<Bq * Nq, 256, 0, stream>>>(
        x, hdiff, mask, wz0, wz1, wp0, wp1, pc, out);
}